// Round 10
// baseline (142.656 us; speedup 1.0000x reference)
//
#include <hip/hip_runtime.h>
#include <hip/hip_bf16.h>
#include <cstdint>
#include <cstddef>

// BesselKANLayer: y[b,o] = sum_{i,d} bessel_d(tanh(x[b,i])) * C[i,o,d]
// b0 == 1 folded into bias; GEMM K = 3*1024.
// GEMM: BM=BN=128, BK=64, 256 thr (4 waves 2x2, wave tile 64x64), grid 512
// = 2 blocks/CU (round-9 TLP mechanism, proven +14%). NEW: B is read
// DIRECTLY global->registers (L2-resident 6MB; reg-double-buffered across
// the __syncthreads, whose fence pins the prefetch — round-4's raw-barrier
// sinking bug fixed). LDS holds only A (32KB dbuf) -> LDS port per body
// drops 1024->384 cyc. XOR swizzle on A, XCD map, setprio kept.

#define BATCH   8192
#define IN_DIM  1024
#define OUT_DIM 1024
#define KDIM    3072
#define NT      48            // KDIM/64 K-tiles
#define BM      128
#define BN      128
#define BUF_SH  8192          // shorts per A buffer: 128*64

typedef __attribute__((ext_vector_type(4))) float f32x4;
typedef __attribute__((ext_vector_type(8))) short bf16x8;

static __device__ __forceinline__ short f2bf(float f) {
    uint32_t u = __float_as_uint(f);
    u += 0x7fffu + ((u >> 16) & 1u);
    return (short)(u >> 16);
}

// ---------------- prep: basis matrix A [8192][3072] bf16 ----------------
__global__ __launch_bounds__(256) void prep_basis(const float* __restrict__ x,
                                                  short* __restrict__ A) {
    int idx = blockIdx.x * 256 + threadIdx.x;
    int b = idx >> 8;
    int i = (idx & 255) << 2;
    const float4 xv = *reinterpret_cast<const float4*>(&x[(size_t)b * IN_DIM + i]);
    float xs[4] = {xv.x, xv.y, xv.z, xv.w};
    short o1[4], o2[4], o3[4];
#pragma unroll
    for (int j = 0; j < 4; ++j) {
        float t  = tanhf(xs[j]);
        float b1 = t + 1.0f;
        float b2 = 3.0f * t * b1 + 1.0f;
        float b3 = 5.0f * t * b2 + b1;
        o1[j] = f2bf(b1); o2[j] = f2bf(b2); o3[j] = f2bf(b3);
    }
    short* row = A + (size_t)b * KDIM;
    *reinterpret_cast<short4*>(&row[i])              = make_short4(o1[0], o1[1], o1[2], o1[3]);
    *reinterpret_cast<short4*>(&row[IN_DIM + i])     = make_short4(o2[0], o2[1], o2[2], o2[3]);
    *reinterpret_cast<short4*>(&row[2 * IN_DIM + i]) = make_short4(o3[0], o3[1], o3[2], o3[3]);
}

// -------- prep: Bt [1024][3072] bf16 transpose + bias[o] = sum_i C[i][o][0] --------
__global__ __launch_bounds__(256) void prep_coeffs(const float* __restrict__ C,
                                                   short* __restrict__ Bt,
                                                   float* __restrict__ bias) {
    __shared__ short tile[3][32][33];
    __shared__ float red[8][32];
    const int i0 = blockIdx.x * 32;
    const int o0 = blockIdx.y * 32;
    const int t  = threadIdx.x;
    const int lo = t & 31;
    const int li = t >> 5;   // 0..7
    float part = 0.0f;
#pragma unroll
    for (int r = 0; r < 4; ++r) {
        int i = li + r * 8;
        const float4 c4 = *reinterpret_cast<const float4*>(
            &C[((size_t)(i0 + i) * OUT_DIM + (o0 + lo)) * 4]);
        tile[0][i][lo] = f2bf(c4.y);
        tile[1][i][lo] = f2bf(c4.z);
        tile[2][i][lo] = f2bf(c4.w);
        part += c4.x;
    }
    red[li][lo] = part;
    __syncthreads();
#pragma unroll
    for (int r = 0; r < 4; ++r) {
        int o = (t >> 5) + r * 8;
        int i = t & 31;
#pragma unroll
        for (int d = 0; d < 3; ++d)
            Bt[(size_t)(o0 + o) * KDIM + d * IN_DIM + (i0 + i)] = tile[d][i][o];
    }
    if (t < 32) {
        float s = 0.0f;
#pragma unroll
        for (int k = 0; k < 8; ++k) s += red[k][t];
        atomicAdd(&bias[o0 + t], s);
    }
}

// ---------------- GEMM: out = A * Bt^T + bias ----------------
__global__ __launch_bounds__(256, 2) void gemm_kan(
    const short* __restrict__ A,     // [BATCH][KDIM]
    const short* __restrict__ Bt,    // [OUT_DIM][KDIM]
    const float* __restrict__ bias,  // [OUT_DIM]
    float* __restrict__ out)         // [BATCH][OUT_DIM]
{
    extern __shared__ short lds[];   // 2 * BUF_SH shorts = 32 KB (A only)

    const int tid  = threadIdx.x;
    const int lane = tid & 63;
    const int wid  = tid >> 6;   // 0..3
    const int wm   = wid >> 1;   // 0..1 (M)
    const int wn   = wid & 1;    // 0..1 (N)

    // XCD map (round-9): grid 512; XCD k -> 16 brow x 4 bcol (B slice 3MB < L2)
    const int bid  = blockIdx.x;
    const int xcd  = bid & 7;
    const int j    = bid >> 3;
    const int brow = ((xcd >> 1) * 16 + (j >> 2)) * BM;
    const int bcol = ((xcd & 1) * 4 + (j & 3)) * BN;

    const int l15 = lane & 15, lh = lane >> 4, l7 = lane & 7;
    const int pc0 = lh ^ l7;            // phys chunk for kk=0 (A swizzle)
    const int pc1 = pc0 ^ 4;            // kk=1

    // A fragment LDS offsets (shorts), swizzle: chunk ^= (row & 7)
    int aoff[4][2];
#pragma unroll
    for (int mi = 0; mi < 4; ++mi) {
        int r = wm * 64 + mi * 16 + l15;
        aoff[mi][0] = r * 64 + pc0 * 8;
        aoff[mi][1] = r * 64 + pc1 * 8;
    }

    // B per-lane base pointers: row = out col (l15), k-chunk lh*8
    const short* bBp[4];
#pragma unroll
    for (int ni = 0; ni < 4; ++ni)
        bBp[ni] = Bt + (size_t)(bcol + wn * 64 + ni * 16 + l15) * KDIM + lh * 8;

    // A staging: 256 thr x 16B = 4KB/instr = 32 rows; 4 instr/tile
    const int srow   = tid >> 3;                    // 0..31
    const int schunk = (tid & 7) ^ (srow & 7);      // inverse-swizzled src chunk

#define STAGE(KT_TILE, B)                                                             \
    do {                                                                              \
        const int kt_ = (KT_TILE) * 64;                                               \
        short* lbase_ = lds + (B) * BUF_SH;                                           \
        _Pragma("unroll")                                                             \
        for (int s_ = 0; s_ < 4; ++s_) {                                              \
            __builtin_amdgcn_global_load_lds(                                         \
                (const __attribute__((address_space(1))) void*)(                      \
                    A + (size_t)(brow + s_ * 32 + srow) * KDIM + kt_ + schunk * 8),   \
                (__attribute__((address_space(3))) void*)(                            \
                    lbase_ + s_ * 2048 + tid * 8), 16, 0, 0);                         \
        }                                                                             \
    } while (0)

// B global->reg loads for tile T into named set BR (issued before the
// barrier that precedes their use; __syncthreads fence pins them here)
#define LOAD_B(T, BR)                                                                 \
    do {                                                                              \
        _Pragma("unroll")                                                             \
        for (int ni = 0; ni < 4; ++ni) {                                              \
            BR[ni][0] = *reinterpret_cast<const bf16x8*>(bBp[ni] + (size_t)(T) * 64);      \
            BR[ni][1] = *reinterpret_cast<const bf16x8*>(bBp[ni] + (size_t)(T) * 64 + 32); \
        }                                                                             \
    } while (0)

// body T: prefetch B(T+1)->spare set, stage A(T+1)->spare buf, ds_read A
// frags(T), 32 MFMA with B(T) regs (ready: last barrier drained vmcnt)
#define BODY(T, BC, BN_, RBUF)                                                        \
    do {                                                                              \
        if ((T) + 1 < NT) LOAD_B((T) + 1, BN_);                                       \
        if ((T) + 1 < NT) STAGE((T) + 1, (RBUF) ^ 1);                                 \
        const short* Ab = lds + (RBUF) * BUF_SH;                                      \
        bf16x8 af[4][2];                                                              \
        _Pragma("unroll")                                                             \
        for (int mi = 0; mi < 4; ++mi) {                                              \
            af[mi][0] = *reinterpret_cast<const bf16x8*>(Ab + aoff[mi][0]);           \
            af[mi][1] = *reinterpret_cast<const bf16x8*>(Ab + aoff[mi][1]);           \
        }                                                                             \
        __builtin_amdgcn_s_setprio(1);                                                \
        _Pragma("unroll")                                                             \
        for (int kk = 0; kk < 2; ++kk)                                                \
            _Pragma("unroll")                                                         \
            for (int mi = 0; mi < 4; ++mi)                                            \
                _Pragma("unroll")                                                     \
                for (int ni = 0; ni < 4; ++ni)                                        \
                    acc[mi][ni] = __builtin_amdgcn_mfma_f32_16x16x32_bf16(            \
                        af[mi][kk], BC[ni][kk], acc[mi][ni], 0, 0, 0);                \
        __builtin_amdgcn_s_setprio(0);                                                \
        if ((T) + 1 < NT) __syncthreads();                                            \
    } while (0)

    // prologue
    f32x4 acc[4][4];
#pragma unroll
    for (int ni = 0; ni < 4; ++ni) {
        float bv = bias[bcol + wn * 64 + ni * 16 + l15];
#pragma unroll
        for (int mi = 0; mi < 4; ++mi)
            acc[mi][ni] = (f32x4){bv, bv, bv, bv};
    }
    bf16x8 b0[4][2], b1[4][2];
    STAGE(0, 0);
    LOAD_B(0, b0);
    __syncthreads();                   // A(0) in LDS, b0 in regs

    // NT = 48 bodies, unrolled x2 for register-set parity
    for (int tt = 0; tt < NT; tt += 2) {
        BODY(tt,     b0, b1, 0);
        BODY(tt + 1, b1, b0, 1);
    }
#undef BODY
#undef LOAD_B
#undef STAGE

    // epilogue: C/D layout col = lane&15, row = (lane>>4)*4 + reg
#pragma unroll
    for (int mi = 0; mi < 4; ++mi) {
#pragma unroll
        for (int r = 0; r < 4; ++r) {
            int row = brow + wm * 64 + mi * 16 + (lane >> 4) * 4 + r;
            float* orow = out + (size_t)row * OUT_DIM + bcol + wn * 64 + l15;
#pragma unroll
            for (int ni = 0; ni < 4; ++ni)
                orow[ni * 16] = acc[mi][ni][r];
        }
    }
}

extern "C" void kernel_launch(void* const* d_in, const int* in_sizes, int n_in,
                              void* d_out, int out_size, void* d_ws, size_t ws_size,
                              hipStream_t stream) {
    (void)in_sizes; (void)n_in; (void)out_size; (void)ws_size;
    const float* x      = (const float*)d_in[0];
    const float* coeffs = (const float*)d_in[1];
    float* out = (float*)d_out;

    char* ws = (char*)d_ws;
    short* A    = (short*)ws;                                        // 48 MB
    short* Bt   = (short*)(ws + (size_t)BATCH * KDIM * 2);           // 6 MB
    float* bias = (float*)(ws + (size_t)BATCH * KDIM * 2
                              + (size_t)OUT_DIM * KDIM * 2);         // 4 KB

    hipFuncSetAttribute((const void*)gemm_kan,
                        hipFuncAttributeMaxDynamicSharedMemorySize,
                        2 * BUF_SH * (int)sizeof(short));

    hipMemsetAsync(bias, 0, OUT_DIM * sizeof(float), stream);
    hipLaunchKernelGGL(prep_basis, dim3(BATCH * IN_DIM / 4 / 256), dim3(256), 0, stream,
                       x, A);
    hipLaunchKernelGGL(prep_coeffs, dim3(IN_DIM / 32, OUT_DIM / 32), dim3(256), 0, stream,
                       coeffs, Bt, bias);
    hipLaunchKernelGGL(gemm_kan, dim3((BATCH / BM) * (OUT_DIM / BN)), dim3(256),
                       2 * BUF_SH * sizeof(short), stream,
                       A, Bt, bias, out);
}

// Round 11
// 103.160 us; speedup vs baseline: 1.3829x; 1.3829x over previous
//
#include <hip/hip_runtime.h>
#include <hip/hip_bf16.h>
#include <cstdint>
#include <cstddef>

// BesselKANLayer: y[b,o] = sum_{i,d} bessel_d(tanh(x[b,i])) * C[i,o,d]
// b0 == 1 folded into bias. FUSED design: no A materialization — the GEMM
// stages raw x (f32) tiles and computes tanh + Bessel recurrence in
// registers between LDS-read and MFMA. Per i-tile of 32: LDS traffic
// 120 KB vs 144 KB for the unfused equivalent, and prep_basis (13us +
// 80MB HBM) is gone. Geometry/control = round 9 (proven): BM=BN=128,
// 4 waves 2x2, dbuf + __syncthreads, 2 blocks/CU, XCD map, XOR swizzles.

#define IN_DIM  1024
#define OUT_DIM 1024
#define KDIM    3072
#define NIT     32            // i-tiles of 32
#define BM      128
#define BN      128
#define BUFB    40960         // bytes per buffer: x 16KB (f32) + B 24KB (bf16 x3 d)

typedef __attribute__((ext_vector_type(4))) float f32x4;
typedef __attribute__((ext_vector_type(8))) short bf16x8;

static __device__ __forceinline__ short f2bf(float f) {
    uint32_t u = __float_as_uint(f);
    u += 0x7fffu + ((u >> 16) & 1u);
    return (short)(u >> 16);
}

static __device__ __forceinline__ float fast_tanh(float x) {
    // tanh(x) = 1 - 2/(e^{2x}+1); saturates correctly at +-inf
    float e = __expf(2.0f * x);
    return 1.0f - 2.0f * __builtin_amdgcn_rcpf(e + 1.0f);
}

static __device__ __forceinline__ bf16x8 pack8(const float* v) {
    union { __hip_bfloat162 h[4]; bf16x8 s; } u;
    u.h[0] = __float22bfloat162_rn(make_float2(v[0], v[1]));
    u.h[1] = __float22bfloat162_rn(make_float2(v[2], v[3]));
    u.h[2] = __float22bfloat162_rn(make_float2(v[4], v[5]));
    u.h[3] = __float22bfloat162_rn(make_float2(v[6], v[7]));
    return u.s;
}

// -------- prep: Bt [1024][3072] bf16 transpose + bias[o] = sum_i C[i][o][0] --------
__global__ __launch_bounds__(256) void prep_coeffs(const float* __restrict__ C,
                                                   short* __restrict__ Bt,
                                                   float* __restrict__ bias) {
    __shared__ short tile[3][32][33];
    __shared__ float red[8][32];
    const int i0 = blockIdx.x * 32;
    const int o0 = blockIdx.y * 32;
    const int t  = threadIdx.x;
    const int lo = t & 31;
    const int li = t >> 5;   // 0..7
    float part = 0.0f;
#pragma unroll
    for (int r = 0; r < 4; ++r) {
        int i = li + r * 8;
        const float4 c4 = *reinterpret_cast<const float4*>(
            &C[((size_t)(i0 + i) * OUT_DIM + (o0 + lo)) * 4]);
        tile[0][i][lo] = f2bf(c4.y);
        tile[1][i][lo] = f2bf(c4.z);
        tile[2][i][lo] = f2bf(c4.w);
        part += c4.x;
    }
    red[li][lo] = part;
    __syncthreads();
#pragma unroll
    for (int r = 0; r < 4; ++r) {
        int o = (t >> 5) + r * 8;
        int i = t & 31;
#pragma unroll
        for (int d = 0; d < 3; ++d)
            Bt[(size_t)(o0 + o) * KDIM + d * IN_DIM + (i0 + i)] = tile[d][i][o];
    }
    if (t < 32) {
        float s = 0.0f;
#pragma unroll
        for (int k = 0; k < 8; ++k) s += red[k][t];
        atomicAdd(&bias[o0 + t], s);
    }
}

// ---------------- fused GEMM: out = basis(tanh(x)) * Bt^T + bias ----------------
__global__ __launch_bounds__(256, 2) void gemm_kan(
    const float* __restrict__ xg,    // [8192][1024] f32
    const short* __restrict__ Bt,    // [OUT_DIM][KDIM] bf16
    const float* __restrict__ bias,  // [OUT_DIM]
    float* __restrict__ out)         // [8192][OUT_DIM]
{
    extern __shared__ char smem[];   // 2 * BUFB = 80 KB

    const int tid  = threadIdx.x;
    const int lane = tid & 63;
    const int wid  = tid >> 6;   // 0..3
    const int wm   = wid >> 1;   // 0..1 (M)
    const int wn   = wid & 1;    // 0..1 (N)

    // XCD map (round-9 proven): XCD k -> 16 brow x 4 bcol
    const int bid  = blockIdx.x;
    const int xcd  = bid & 7;
    const int j    = bid >> 3;
    const int brow = ((xcd >> 1) * 16 + (j >> 2)) * BM;
    const int bcol = ((xcd & 1) * 4 + (j & 3)) * BN;

    const int l15 = lane & 15, lh = lane >> 4;

    // x fragment read offsets (floats): row-major [128][32] f32, 8 subs of
    // 16B per row, swizzle sub ^= row&7  (2-way free, verified bank math)
    int xo0[4], xo1[4];
#pragma unroll
    for (int mi = 0; mi < 4; ++mi) {
        int r = wm * 64 + mi * 16 + l15;
        xo0[mi] = r * 32 + (((2 * lh)     ^ (l15 & 7)) * 4);
        xo1[mi] = r * 32 + (((2 * lh + 1) ^ (l15 & 7)) * 4);
    }
    // B fragment read offsets (shorts): [3][128][32] bf16, 4 chunks of 16B
    // per row, swizzle chunk ^= (row>>1)&3  (2-way free, verified)
    const int pcb = lh ^ ((l15 >> 1) & 3);
    int boff[4][3];
#pragma unroll
    for (int ni = 0; ni < 4; ++ni) {
        int r = wn * 64 + ni * 16 + l15;
#pragma unroll
        for (int d = 0; d < 3; ++d)
            boff[ni][d] = d * 4096 + r * 32 + pcb * 8;
    }

    // staging geometry (inverse swizzles on global source, linear LDS dest)
    const int xsrow = tid >> 3;                     // 0..31 per instr
    const int xlsub = (tid & 7) ^ (xsrow & 7);
    const int bsrow = tid >> 2;                     // 0..63 per instr
    const int blc   = (tid & 3) ^ ((tid >> 3) & 3); // (bsrow>>1)&3 == (tid>>3)&3

#define STAGE_X(IT, PB)                                                               \
    do {                                                                              \
        float* xd_ = (float*)(smem + (PB) * BUFB);                                    \
        _Pragma("unroll")                                                             \
        for (int s_ = 0; s_ < 4; ++s_) {                                              \
            __builtin_amdgcn_global_load_lds(                                         \
                (const __attribute__((address_space(1))) void*)(                      \
                    xg + (size_t)(brow + s_ * 32 + xsrow) * IN_DIM + (IT) * 32        \
                       + xlsub * 4),                                                  \
                (__attribute__((address_space(3))) void*)(                            \
                    xd_ + s_ * 1024 + tid * 4), 16, 0, 0);                            \
        }                                                                             \
    } while (0)

#define STAGE_B(IT, PB)                                                               \
    do {                                                                              \
        short* bd_ = (short*)(smem + (PB) * BUFB + 16384);                            \
        _Pragma("unroll")                                                             \
        for (int d_ = 0; d_ < 3; ++d_) {                                              \
            _Pragma("unroll")                                                         \
            for (int s_ = 0; s_ < 2; ++s_) {                                          \
                __builtin_amdgcn_global_load_lds(                                     \
                    (const __attribute__((address_space(1))) void*)(                  \
                        Bt + (size_t)(bcol + s_ * 64 + bsrow) * KDIM + d_ * IN_DIM    \
                           + (IT) * 32 + blc * 8),                                    \
                    (__attribute__((address_space(3))) void*)(                        \
                        bd_ + d_ * 4096 + s_ * 2048 + tid * 8), 16, 0, 0);            \
            }                                                                         \
        }                                                                             \
    } while (0)

// body T: stage(T+1) | read B frags | per-mi {read x, tanh+recurrence,
// pack bf16, 12 MFMA} | __syncthreads (compiler manages lgkm interleave)
#define BODY(T, P)                                                                    \
    do {                                                                              \
        if ((T) + 1 < NIT) { STAGE_X((T) + 1, (P) ^ 1); STAGE_B((T) + 1, (P) ^ 1); }  \
        const float* xb_ = (const float*)(smem + (P) * BUFB);                         \
        const short* bb_ = (const short*)(smem + (P) * BUFB + 16384);                 \
        bf16x8 bfr[4][3];                                                             \
        _Pragma("unroll")                                                             \
        for (int ni = 0; ni < 4; ++ni)                                                \
            _Pragma("unroll")                                                         \
            for (int d = 0; d < 3; ++d)                                               \
                bfr[ni][d] = *reinterpret_cast<const bf16x8*>(bb_ + boff[ni][d]);     \
        _Pragma("unroll")                                                             \
        for (int mi = 0; mi < 4; ++mi) {                                              \
            float4 f0 = *reinterpret_cast<const float4*>(xb_ + xo0[mi]);              \
            float4 f1 = *reinterpret_cast<const float4*>(xb_ + xo1[mi]);              \
            float xv[8] = {f0.x, f0.y, f0.z, f0.w, f1.x, f1.y, f1.z, f1.w};           \
            float c1[8], c2[8], c3[8];                                                \
            _Pragma("unroll")                                                         \
            for (int jj = 0; jj < 8; ++jj) {                                          \
                float t_ = fast_tanh(xv[jj]);                                         \
                c1[jj] = t_ + 1.0f;                                                   \
                c2[jj] = 3.0f * t_ * c1[jj] + 1.0f;                                   \
                c3[jj] = 5.0f * t_ * c2[jj] + c1[jj];                                 \
            }                                                                         \
            bf16x8 a1 = pack8(c1), a2 = pack8(c2), a3 = pack8(c3);                    \
            __builtin_amdgcn_s_setprio(1);                                            \
            _Pragma("unroll")                                                         \
            for (int ni = 0; ni < 4; ++ni) {                                          \
                acc[mi][ni] = __builtin_amdgcn_mfma_f32_16x16x32_bf16(                \
                    a1, bfr[ni][0], acc[mi][ni], 0, 0, 0);                            \
                acc[mi][ni] = __builtin_amdgcn_mfma_f32_16x16x32_bf16(                \
                    a2, bfr[ni][1], acc[mi][ni], 0, 0, 0);                            \
                acc[mi][ni] = __builtin_amdgcn_mfma_f32_16x16x32_bf16(                \
                    a3, bfr[ni][2], acc[mi][ni], 0, 0, 0);                            \
            }                                                                         \
            __builtin_amdgcn_s_setprio(0);                                            \
        }                                                                             \
        if ((T) + 1 < NIT) __syncthreads();                                           \
    } while (0)

    // prologue
    f32x4 acc[4][4];
#pragma unroll
    for (int ni = 0; ni < 4; ++ni) {
        float bv = bias[bcol + wn * 64 + ni * 16 + l15];
#pragma unroll
        for (int mi = 0; mi < 4; ++mi)
            acc[mi][ni] = (f32x4){bv, bv, bv, bv};
    }
    STAGE_X(0, 0);
    STAGE_B(0, 0);
    __syncthreads();                   // tile 0 in LDS

    for (int tt = 0; tt < NIT; tt += 2) {
        BODY(tt,     0);
        BODY(tt + 1, 1);
    }
#undef BODY
#undef STAGE_X
#undef STAGE_B

    // epilogue: C/D layout col = lane&15, row = (lane>>4)*4 + reg
#pragma unroll
    for (int mi = 0; mi < 4; ++mi) {
#pragma unroll
        for (int r = 0; r < 4; ++r) {
            int row = brow + wm * 64 + mi * 16 + (lane >> 4) * 4 + r;
            float* orow = out + (size_t)row * OUT_DIM + bcol + wn * 64 + l15;
#pragma unroll
            for (int ni = 0; ni < 4; ++ni)
                orow[ni * 16] = acc[mi][ni][r];
        }
    }
}

extern "C" void kernel_launch(void* const* d_in, const int* in_sizes, int n_in,
                              void* d_out, int out_size, void* d_ws, size_t ws_size,
                              hipStream_t stream) {
    (void)in_sizes; (void)n_in; (void)out_size; (void)ws_size;
    const float* x      = (const float*)d_in[0];
    const float* coeffs = (const float*)d_in[1];
    float* out = (float*)d_out;

    char* ws = (char*)d_ws;
    short* Bt   = (short*)ws;                                        // 6 MB
    float* bias = (float*)(ws + (size_t)OUT_DIM * KDIM * 2);         // 4 KB

    hipFuncSetAttribute((const void*)gemm_kan,
                        hipFuncAttributeMaxDynamicSharedMemorySize, 2 * BUFB);

    hipMemsetAsync(bias, 0, OUT_DIM * sizeof(float), stream);
    hipLaunchKernelGGL(prep_coeffs, dim3(IN_DIM / 32, OUT_DIM / 32), dim3(256), 0, stream,
                       coeffs, Bt, bias);
    hipLaunchKernelGGL(gemm_kan, dim3((8192 / BM) * (OUT_DIM / BN)), dim3(256),
                       2 * BUFB, stream,
                       x, Bt, bias, out);
}

// Round 12
// 53.739 us; speedup vs baseline: 2.6546x; 1.9196x over previous
//
#include <hip/hip_runtime.h>
#include <hip/hip_bf16.h>
#include <cstdint>
#include <cstddef>

// BesselKANLayer via POWER BASIS + INT8 GEMM.
// y[b,o] = sum_p (sum_i mu_p[i,o] * t^p),  t = tanh(x),  p = 1..3,
// mu1 = c1+3c2+6c3, mu2 = 3c2+15c3, mu3 = 15c3, bias = sum_i(c0+c1+c2+c3).
// All t^p in [-1,1] -> i8 quant A: aq = rni(s_p * t^p); B: bq = rni(t_p*mu_p)
// with s_p*t_p = S common -> single i32 accumulator, y = acc/S + bias.
// GEMM geometry = round 9 (proven port-saturated): BM=BN=128, 4 waves 2x2,
// dbuf LDS, 2 blocks/CU, XCD map, XOR swizzle — byte layout identical
// (128B rows, 16B chunks), BK = 128 bytes, mfma_i32_16x16x64_i8 (2x rate).
// Port bytes/FLOP halve: 0.0458 -> 0.0229.

#define BATCH   8192
#define IN_DIM  1024
#define OUT_DIM 1024
#define KB      3072          // K in bytes (= elements, i8)
#define NT      24            // K-tiles of 128 bytes
#define BM      128
#define BN      128
#define BUFB    32768         // bytes per buffer: A 128*128 + B 128*128

// scales: sigma_c = 1/4096; t_p = 127/(6*sigma_p); S = 127*t_2
#define SA1 56.307f
#define SA2 127.0f
#define SA3 124.534f
#define TB1 12783.33f
#define TB2 5667.68f
#define TB3 5779.91f
#define INV_S 1.389284e-6f    // 1/(127*5667.68)

typedef __attribute__((ext_vector_type(4))) int   i32x4;

static __device__ __forceinline__ int q8(float v) {
    int q = __float2int_rn(v);
    return q < -127 ? -127 : (q > 127 ? 127 : q);
}

// ---------- prep: Aq [8192][3072] i8, k = p*1024 + i, aq = rni(s_p t^p) ----------
__global__ __launch_bounds__(256) void prep_basis(const float* __restrict__ x,
                                                  int8_t* __restrict__ Aq) {
    int idx = blockIdx.x * 256 + threadIdx.x;
    int b = idx >> 8;
    int i = (idx & 255) << 2;
    const float4 xv = *reinterpret_cast<const float4*>(&x[(size_t)b * IN_DIM + i]);
    float xs[4] = {xv.x, xv.y, xv.z, xv.w};
    int w1 = 0, w2 = 0, w3 = 0;
#pragma unroll
    for (int j = 0; j < 4; ++j) {
        float t  = tanhf(xs[j]);
        float t2 = t * t;
        float t3 = t2 * t;
        w1 |= (q8(SA1 * t)  & 0xff) << (8 * j);
        w2 |= (q8(SA2 * t2) & 0xff) << (8 * j);
        w3 |= (q8(SA3 * t3) & 0xff) << (8 * j);
    }
    int* row = (int*)(Aq + (size_t)b * KB);
    int c = i >> 2;
    row[c]       = w1;
    row[256 + c] = w2;
    row[512 + c] = w3;
}

// ---- prep: Bq [1024][3072] i8 (transposed), bq = rni(t_p mu_p); bias f32 ----
__global__ __launch_bounds__(256) void prep_coeffs(const float* __restrict__ C,
                                                   int8_t* __restrict__ Bq,
                                                   float* __restrict__ bias) {
    __shared__ int8_t tile[3][32][33];
    __shared__ float red[8][32];
    const int i0 = blockIdx.x * 32;
    const int o0 = blockIdx.y * 32;
    const int t  = threadIdx.x;
    const int lo = t & 31;
    const int li = t >> 5;   // 0..7
    float part = 0.0f;
#pragma unroll
    for (int r = 0; r < 4; ++r) {
        int i = li + r * 8;
        const float4 c4 = *reinterpret_cast<const float4*>(
            &C[((size_t)(i0 + i) * OUT_DIM + (o0 + lo)) * 4]);
        tile[0][i][lo] = (int8_t)q8(TB1 * (c4.y + 3.0f * c4.z + 6.0f * c4.w));
        tile[1][i][lo] = (int8_t)q8(TB2 * (3.0f * c4.z + 15.0f * c4.w));
        tile[2][i][lo] = (int8_t)q8(TB3 * (15.0f * c4.w));
        part += c4.x + c4.y + c4.z + c4.w;
    }
    red[li][lo] = part;
    __syncthreads();
#pragma unroll
    for (int r = 0; r < 4; ++r) {
        int o = (t >> 5) + r * 8;
        int i = t & 31;
#pragma unroll
        for (int d = 0; d < 3; ++d)
            Bq[(size_t)(o0 + o) * KB + d * IN_DIM + (i0 + i)] = tile[d][i][o];
    }
    if (t < 32) {
        float s = 0.0f;
#pragma unroll
        for (int k = 0; k < 8; ++k) s += red[k][t];
        atomicAdd(&bias[o0 + t], s);
    }
}

// ---------------- GEMM i8: out = (Aq * Bq^T) * INV_S + bias ----------------
__global__ __launch_bounds__(256, 2) void gemm_kan(
    const int8_t* __restrict__ Aq,   // [BATCH][KB]
    const int8_t* __restrict__ Bq,   // [OUT_DIM][KB]
    const float* __restrict__ bias,  // [OUT_DIM]
    float* __restrict__ out)         // [BATCH][OUT_DIM]
{
    extern __shared__ char smem[];   // 2 * BUFB = 64 KB

    const int tid  = threadIdx.x;
    const int lane = tid & 63;
    const int wid  = tid >> 6;   // 0..3
    const int wm   = wid >> 1;   // 0..1 (M)
    const int wn   = wid & 1;    // 0..1 (N)

    // XCD map (round-9 proven): XCD k -> 16 brow x 4 bcol
    const int bid  = blockIdx.x;
    const int xcd  = bid & 7;
    const int j    = bid >> 3;
    const int brow = ((xcd >> 1) * 16 + (j >> 2)) * BM;
    const int bcol = ((xcd & 1) * 4 + (j & 3)) * BN;

    const int l15 = lane & 15, lh = lane >> 4, l7 = lane & 7;
    const int pc0 = lh ^ l7;            // phys 16B-chunk, kk=0 (swizzled)
    const int pc1 = pc0 ^ 4;            // kk=1

    // fragment LDS byte offsets; rows are 128B, chunk ^= (row & 7)
    int aoff[4][2], boff[4][2];
#pragma unroll
    for (int mi = 0; mi < 4; ++mi) {
        int r = wm * 64 + mi * 16 + l15;
        aoff[mi][0] = r * 128 + pc0 * 16;
        aoff[mi][1] = r * 128 + pc1 * 16;
    }
#pragma unroll
    for (int ni = 0; ni < 4; ++ni) {
        int r = wn * 64 + ni * 16 + l15;
        boff[ni][0] = 16384 + r * 128 + pc0 * 16;
        boff[ni][1] = 16384 + r * 128 + pc1 * 16;
    }

    // staging: 256 thr x 16B = 4KB/instr = 32 rows; A 4 instr + B 4 instr
    const int srow   = tid >> 3;                    // 0..31
    const int schunk = (tid & 7) ^ (srow & 7);      // inverse-swizzled src chunk

#define STAGE(KT_TILE, P)                                                             \
    do {                                                                              \
        const int kt_ = (KT_TILE) * 128;                                              \
        char* lbase_ = smem + (P) * BUFB;                                             \
        _Pragma("unroll")                                                             \
        for (int s_ = 0; s_ < 4; ++s_) {                                              \
            __builtin_amdgcn_global_load_lds(                                         \
                (const __attribute__((address_space(1))) void*)(                      \
                    Aq + (size_t)(brow + s_ * 32 + srow) * KB + kt_ + schunk * 16),   \
                (__attribute__((address_space(3))) void*)(                            \
                    lbase_ + s_ * 4096 + tid * 16), 16, 0, 0);                        \
        }                                                                             \
        _Pragma("unroll")                                                             \
        for (int s_ = 0; s_ < 4; ++s_) {                                              \
            __builtin_amdgcn_global_load_lds(                                         \
                (const __attribute__((address_space(1))) void*)(                      \
                    Bq + (size_t)(bcol + s_ * 32 + srow) * KB + kt_ + schunk * 16),   \
                (__attribute__((address_space(3))) void*)(                            \
                    lbase_ + 16384 + s_ * 4096 + tid * 16), 16, 0, 0);                \
        }                                                                             \
    } while (0)

    // prologue
    i32x4 acc[4][4];
#pragma unroll
    for (int mi = 0; mi < 4; ++mi)
#pragma unroll
        for (int ni = 0; ni < 4; ++ni)
            acc[mi][ni] = (i32x4){0, 0, 0, 0};

    STAGE(0, 0);
    __syncthreads();                   // tile 0 in LDS

    for (int t = 0; t < NT; ++t) {
        const int p = t & 1;
        if (t + 1 < NT) STAGE(t + 1, p ^ 1);    // prefetch next tile

        const char* lb = smem + p * BUFB;
        i32x4 af[4][2], bfr[4][2];
#pragma unroll
        for (int mi = 0; mi < 4; ++mi) {
            af[mi][0] = *reinterpret_cast<const i32x4*>(lb + aoff[mi][0]);
            af[mi][1] = *reinterpret_cast<const i32x4*>(lb + aoff[mi][1]);
        }
#pragma unroll
        for (int ni = 0; ni < 4; ++ni) {
            bfr[ni][0] = *reinterpret_cast<const i32x4*>(lb + boff[ni][0]);
            bfr[ni][1] = *reinterpret_cast<const i32x4*>(lb + boff[ni][1]);
        }
        __builtin_amdgcn_s_setprio(1);
#pragma unroll
        for (int kk = 0; kk < 2; ++kk)
#pragma unroll
            for (int mi = 0; mi < 4; ++mi)
#pragma unroll
                for (int ni = 0; ni < 4; ++ni)
                    acc[mi][ni] = __builtin_amdgcn_mfma_i32_16x16x64_i8(
                        af[mi][kk], bfr[ni][kk], acc[mi][ni], 0, 0, 0);
        __builtin_amdgcn_s_setprio(0);

        if (t + 1 < NT) __syncthreads();
    }
#undef STAGE

    // epilogue: C/D layout col = lane&15, row = (lane>>4)*4 + reg
    float bv[4];
#pragma unroll
    for (int ni = 0; ni < 4; ++ni)
        bv[ni] = bias[bcol + wn * 64 + ni * 16 + l15];
#pragma unroll
    for (int mi = 0; mi < 4; ++mi) {
#pragma unroll
        for (int r = 0; r < 4; ++r) {
            int row = brow + wm * 64 + mi * 16 + (lane >> 4) * 4 + r;
            float* orow = out + (size_t)row * OUT_DIM + bcol + wn * 64 + l15;
#pragma unroll
            for (int ni = 0; ni < 4; ++ni)
                orow[ni * 16] = (float)acc[mi][ni][r] * INV_S + bv[ni];
        }
    }
}

extern "C" void kernel_launch(void* const* d_in, const int* in_sizes, int n_in,
                              void* d_out, int out_size, void* d_ws, size_t ws_size,
                              hipStream_t stream) {
    (void)in_sizes; (void)n_in; (void)out_size; (void)ws_size;
    const float* x      = (const float*)d_in[0];
    const float* coeffs = (const float*)d_in[1];
    float* out = (float*)d_out;

    char* ws = (char*)d_ws;
    int8_t* Aq  = (int8_t*)ws;                                       // 24 MB
    int8_t* Bq  = (int8_t*)(ws + (size_t)BATCH * KB);                // 3 MB
    float* bias = (float*)(ws + (size_t)BATCH * KB + (size_t)OUT_DIM * KB);

    hipFuncSetAttribute((const void*)gemm_kan,
                        hipFuncAttributeMaxDynamicSharedMemorySize, 2 * BUFB);

    hipMemsetAsync(bias, 0, OUT_DIM * sizeof(float), stream);
    hipLaunchKernelGGL(prep_basis, dim3(BATCH * IN_DIM / 4 / 256), dim3(256), 0, stream,
                       x, Aq);
    hipLaunchKernelGGL(prep_coeffs, dim3(IN_DIM / 32, OUT_DIM / 32), dim3(256), 0, stream,
                       coeffs, Bq, bias);
    hipLaunchKernelGGL(gemm_kan, dim3((BATCH / BM) * (OUT_DIM / BN)), dim3(256),
                       2 * BUFB, stream,
                       Aq, Bq, bias, out);
}

// Round 13
// 49.597 us; speedup vs baseline: 2.8763x; 1.0835x over previous
//
#include <hip/hip_runtime.h>
#include <hip/hip_bf16.h>
#include <cstdint>
#include <cstddef>

// BesselKANLayer via POWER BASIS + INT8 GEMM (round-12 proven, 53.7us).
// y[b,o] = sum_p (sum_i mu_p[i,o] * t^p),  t = tanh(x),  p = 1..3,
// mu1 = c1+3c2+6c3, mu2 = 3c2+15c3, mu3 = 15c3, bias = sum_i(c0+..+c3).
// t^p in [-1,1] -> i8 quant both sides, common product scale S, i32 acc.
// GEMM geometry = round 9 (port-saturated): BM=BN=128, 4 waves 2x2, dbuf
// LDS, 2 blocks/CU, XCD map, XOR swizzle, BK=128B, mfma_i32_16x16x64_i8.
// Round 13: merged prep kernel (1 launch), 8-elem/thread basis + fast tanh.

#define BATCH   8192
#define IN_DIM  1024
#define OUT_DIM 1024
#define KB      3072          // K in bytes (= elements, i8)
#define NT      24            // K-tiles of 128 bytes
#define BM      128
#define BN      128
#define BUFB    32768         // bytes per buffer: A 128*128 + B 128*128
#define NB_BASIS 4096         // basis blocks: 8192*1024/8/256

// scales: sigma_c = 1/4096; t_p = 127/(6*sigma_p); S = 127*t_2
#define SA1 56.307f
#define SA2 127.0f
#define SA3 124.534f
#define TB1 12783.33f
#define TB2 5667.68f
#define TB3 5779.91f
#define INV_S 1.389284e-6f    // 1/(127*5667.68)

typedef __attribute__((ext_vector_type(4))) int i32x4;

static __device__ __forceinline__ int q8(float v) {
    int q = __float2int_rn(v);
    return q < -127 ? -127 : (q > 127 ? 127 : q);
}

static __device__ __forceinline__ float fast_tanh(float x) {
    // tanh(x) = 1 - 2/(e^{2x}+1); correct saturation at +-inf
    float e = __expf(2.0f * x);
    return 1.0f - 2.0f * __builtin_amdgcn_rcpf(e + 1.0f);
}

// ---- merged prep: blocks [0,4096) -> Aq basis; [4096,5120) -> Bq + bias ----
__global__ __launch_bounds__(256) void prep_all(const float* __restrict__ x,
                                                const float* __restrict__ C,
                                                int8_t* __restrict__ Aq,
                                                int8_t* __restrict__ Bq,
                                                float* __restrict__ bias) {
    const int t = threadIdx.x;
    if (blockIdx.x < NB_BASIS) {
        // Aq [8192][3072] i8, k = (p-1)*1024 + i, aq = rni(s_p t^p); 8 elem/thr
        int idx = blockIdx.x * 256 + t;
        int b = idx >> 7;               // 128 threads cover a 1024-row
        int i = (idx & 127) << 3;
        const float* xr = x + (size_t)b * IN_DIM + i;
        const float4 v0 = *reinterpret_cast<const float4*>(xr);
        const float4 v1 = *reinterpret_cast<const float4*>(xr + 4);
        float xs[8] = {v0.x, v0.y, v0.z, v0.w, v1.x, v1.y, v1.z, v1.w};
        int w1[2] = {0, 0}, w2[2] = {0, 0}, w3[2] = {0, 0};
#pragma unroll
        for (int j = 0; j < 8; ++j) {
            float tv = fast_tanh(xs[j]);
            float t2 = tv * tv;
            float t3 = t2 * tv;
            int h = j >> 2, s = 8 * (j & 3);
            w1[h] |= (q8(SA1 * tv) & 0xff) << s;
            w2[h] |= (q8(SA2 * t2) & 0xff) << s;
            w3[h] |= (q8(SA3 * t3) & 0xff) << s;
        }
        int* row = (int*)(Aq + (size_t)b * KB);
        int c = i >> 2;                 // even -> 8B aligned
        *reinterpret_cast<int2*>(&row[c])       = make_int2(w1[0], w1[1]);
        *reinterpret_cast<int2*>(&row[256 + c]) = make_int2(w2[0], w2[1]);
        *reinterpret_cast<int2*>(&row[512 + c]) = make_int2(w3[0], w3[1]);
    } else {
        // Bq [1024][3072] i8 transposed, bq = rni(t_p mu_p); bias partials
        __shared__ int8_t tile[3][32][33];
        __shared__ float red[8][32];
        const int cb = blockIdx.x - NB_BASIS;   // 0..1023
        const int i0 = (cb & 31) * 32;
        const int o0 = (cb >> 5) * 32;
        const int lo = t & 31;
        const int li = t >> 5;   // 0..7
        float part = 0.0f;
#pragma unroll
        for (int r = 0; r < 4; ++r) {
            int i = li + r * 8;
            const float4 c4 = *reinterpret_cast<const float4*>(
                &C[((size_t)(i0 + i) * OUT_DIM + (o0 + lo)) * 4]);
            tile[0][i][lo] = (int8_t)q8(TB1 * (c4.y + 3.0f * c4.z + 6.0f * c4.w));
            tile[1][i][lo] = (int8_t)q8(TB2 * (3.0f * c4.z + 15.0f * c4.w));
            tile[2][i][lo] = (int8_t)q8(TB3 * (15.0f * c4.w));
            part += c4.x + c4.y + c4.z + c4.w;
        }
        red[li][lo] = part;
        __syncthreads();
#pragma unroll
        for (int r = 0; r < 4; ++r) {
            int o = (t >> 5) + r * 8;
            int i = t & 31;
#pragma unroll
            for (int d = 0; d < 3; ++d)
                Bq[(size_t)(o0 + o) * KB + d * IN_DIM + (i0 + i)] = tile[d][i][o];
        }
        if (t < 32) {
            float s = 0.0f;
#pragma unroll
            for (int k = 0; k < 8; ++k) s += red[k][t];
            atomicAdd(&bias[o0 + t], s);
        }
    }
}

// ---------------- GEMM i8: out = (Aq * Bq^T) * INV_S + bias ----------------
__global__ __launch_bounds__(256, 2) void gemm_kan(
    const int8_t* __restrict__ Aq,   // [BATCH][KB]
    const int8_t* __restrict__ Bq,   // [OUT_DIM][KB]
    const float* __restrict__ bias,  // [OUT_DIM]
    float* __restrict__ out)         // [BATCH][OUT_DIM]
{
    extern __shared__ char smem[];   // 2 * BUFB = 64 KB

    const int tid  = threadIdx.x;
    const int lane = tid & 63;
    const int wid  = tid >> 6;   // 0..3
    const int wm   = wid >> 1;   // 0..1 (M)
    const int wn   = wid & 1;    // 0..1 (N)

    // XCD map (round-9 proven): XCD k -> 16 brow x 4 bcol
    const int bid  = blockIdx.x;
    const int xcd  = bid & 7;
    const int j    = bid >> 3;
    const int brow = ((xcd >> 1) * 16 + (j >> 2)) * BM;
    const int bcol = ((xcd & 1) * 4 + (j & 3)) * BN;

    const int l15 = lane & 15, lh = lane >> 4, l7 = lane & 7;
    const int pc0 = lh ^ l7;            // phys 16B-chunk, kk=0 (swizzled)
    const int pc1 = pc0 ^ 4;            // kk=1

    // fragment LDS byte offsets; rows are 128B, chunk ^= (row & 7)
    int aoff[4][2], boff[4][2];
#pragma unroll
    for (int mi = 0; mi < 4; ++mi) {
        int r = wm * 64 + mi * 16 + l15;
        aoff[mi][0] = r * 128 + pc0 * 16;
        aoff[mi][1] = r * 128 + pc1 * 16;
    }
#pragma unroll
    for (int ni = 0; ni < 4; ++ni) {
        int r = wn * 64 + ni * 16 + l15;
        boff[ni][0] = 16384 + r * 128 + pc0 * 16;
        boff[ni][1] = 16384 + r * 128 + pc1 * 16;
    }

    // staging: 256 thr x 16B = 4KB/instr = 32 rows; A 4 instr + B 4 instr
    const int srow   = tid >> 3;                    // 0..31
    const int schunk = (tid & 7) ^ (srow & 7);      // inverse-swizzled src chunk

#define STAGE(KT_TILE, P)                                                             \
    do {                                                                              \
        const int kt_ = (KT_TILE) * 128;                                              \
        char* lbase_ = smem + (P) * BUFB;                                             \
        _Pragma("unroll")                                                             \
        for (int s_ = 0; s_ < 4; ++s_) {                                              \
            __builtin_amdgcn_global_load_lds(                                         \
                (const __attribute__((address_space(1))) void*)(                      \
                    Aq + (size_t)(brow + s_ * 32 + srow) * KB + kt_ + schunk * 16),   \
                (__attribute__((address_space(3))) void*)(                            \
                    lbase_ + s_ * 4096 + tid * 16), 16, 0, 0);                        \
        }                                                                             \
        _Pragma("unroll")                                                             \
        for (int s_ = 0; s_ < 4; ++s_) {                                              \
            __builtin_amdgcn_global_load_lds(                                         \
                (const __attribute__((address_space(1))) void*)(                      \
                    Bq + (size_t)(bcol + s_ * 32 + srow) * KB + kt_ + schunk * 16),   \
                (__attribute__((address_space(3))) void*)(                            \
                    lbase_ + 16384 + s_ * 4096 + tid * 16), 16, 0, 0);                \
        }                                                                             \
    } while (0)

    // prologue
    i32x4 acc[4][4];
#pragma unroll
    for (int mi = 0; mi < 4; ++mi)
#pragma unroll
        for (int ni = 0; ni < 4; ++ni)
            acc[mi][ni] = (i32x4){0, 0, 0, 0};

    STAGE(0, 0);
    __syncthreads();                   // tile 0 in LDS

    for (int t = 0; t < NT; ++t) {
        const int p = t & 1;
        if (t + 1 < NT) STAGE(t + 1, p ^ 1);    // prefetch next tile

        const char* lb = smem + p * BUFB;
        i32x4 af[4][2], bfr[4][2];
#pragma unroll
        for (int mi = 0; mi < 4; ++mi) {
            af[mi][0] = *reinterpret_cast<const i32x4*>(lb + aoff[mi][0]);
            af[mi][1] = *reinterpret_cast<const i32x4*>(lb + aoff[mi][1]);
        }
#pragma unroll
        for (int ni = 0; ni < 4; ++ni) {
            bfr[ni][0] = *reinterpret_cast<const i32x4*>(lb + boff[ni][0]);
            bfr[ni][1] = *reinterpret_cast<const i32x4*>(lb + boff[ni][1]);
        }
        __builtin_amdgcn_s_setprio(1);
#pragma unroll
        for (int kk = 0; kk < 2; ++kk)
#pragma unroll
            for (int mi = 0; mi < 4; ++mi)
#pragma unroll
                for (int ni = 0; ni < 4; ++ni)
                    acc[mi][ni] = __builtin_amdgcn_mfma_i32_16x16x64_i8(
                        af[mi][kk], bfr[ni][kk], acc[mi][ni], 0, 0, 0);
        __builtin_amdgcn_s_setprio(0);

        if (t + 1 < NT) __syncthreads();
    }
#undef STAGE

    // epilogue: C/D layout col = lane&15, row = (lane>>4)*4 + reg
    float bv[4];
#pragma unroll
    for (int ni = 0; ni < 4; ++ni)
        bv[ni] = bias[bcol + wn * 64 + ni * 16 + l15];
#pragma unroll
    for (int mi = 0; mi < 4; ++mi) {
#pragma unroll
        for (int r = 0; r < 4; ++r) {
            int row = brow + wm * 64 + mi * 16 + (lane >> 4) * 4 + r;
            float* orow = out + (size_t)row * OUT_DIM + bcol + wn * 64 + l15;
#pragma unroll
            for (int ni = 0; ni < 4; ++ni)
                orow[ni * 16] = (float)acc[mi][ni][r] * INV_S + bv[ni];
        }
    }
}

extern "C" void kernel_launch(void* const* d_in, const int* in_sizes, int n_in,
                              void* d_out, int out_size, void* d_ws, size_t ws_size,
                              hipStream_t stream) {
    (void)in_sizes; (void)n_in; (void)out_size; (void)ws_size;
    const float* x      = (const float*)d_in[0];
    const float* coeffs = (const float*)d_in[1];
    float* out = (float*)d_out;

    char* ws = (char*)d_ws;
    int8_t* Aq  = (int8_t*)ws;                                       // 24 MB
    int8_t* Bq  = (int8_t*)(ws + (size_t)BATCH * KB);                // 3 MB
    float* bias = (float*)(ws + (size_t)BATCH * KB + (size_t)OUT_DIM * KB);

    hipFuncSetAttribute((const void*)gemm_kan,
                        hipFuncAttributeMaxDynamicSharedMemorySize, 2 * BUFB);

    hipMemsetAsync(bias, 0, OUT_DIM * sizeof(float), stream);
    hipLaunchKernelGGL(prep_all, dim3(NB_BASIS + 1024), dim3(256), 0, stream,
                       x, coeffs, Aq, Bq, bias);
    hipLaunchKernelGGL(gemm_kan, dim3((BATCH / BM) * (OUT_DIM / BN)), dim3(256),
                       2 * BUFB, stream,
                       Aq, Bq, bias, out);
}